// Round 1
// 1450.494 us; speedup vs baseline: 1.0462x; 1.0462x over previous
//
#include <hip/hip_runtime.h>

#define NROWS 8192      // BS*HEADS
#define NKEYS 512
#define KNN   32

// ---------------------------------------------------------------------------
// GEMM (NT, fp32): C[M,N] = A[M,K] * B[N,K]^T (+bias[n])
// BM=128, BN=64, BK=16, 256 threads, 8x4 outputs/thread.  Used for the
// 16384x512 score GEMM (1024 blocks -> 4 blocks/CU).
// ---------------------------------------------------------------------------
__global__ __launch_bounds__(256)
void gemm_nt_f32(const float* __restrict__ A, int lda,
                 const float* __restrict__ B, int ldb,
                 float* __restrict__ C, int ldc,
                 const float* __restrict__ bias, int K) {
  __shared__ float As[16][132];   // [k][m]
  __shared__ float Bs[16][68];    // [k][n]
  const int tid = threadIdx.x;
  const int tx = tid & 15;        // -> n
  const int ty = tid >> 4;        // -> m
  const int m0 = blockIdx.y * 128;
  const int n0 = blockIdx.x * 64;
  const int am = tid >> 1;        // 0..127
  const int ak = (tid & 1) * 8;   // 0 or 8
  const int bn = tid >> 2;        // 0..63
  const int bk = (tid & 3) * 4;   // 0,4,8,12

  float acc[8][4];
  #pragma unroll
  for (int i = 0; i < 8; i++)
    #pragma unroll
    for (int j = 0; j < 4; j++) acc[i][j] = 0.f;

  const float* Arow = A + (size_t)(m0 + am) * lda + ak;
  const float* Brow = B + (size_t)(n0 + bn) * ldb + bk;

  for (int kt = 0; kt < K; kt += 16) {
    float4 a0 = *(const float4*)(Arow + kt);
    float4 a1 = *(const float4*)(Arow + kt + 4);
    float4 b0 = *(const float4*)(Brow + kt);
    As[ak+0][am] = a0.x; As[ak+1][am] = a0.y; As[ak+2][am] = a0.z; As[ak+3][am] = a0.w;
    As[ak+4][am] = a1.x; As[ak+5][am] = a1.y; As[ak+6][am] = a1.z; As[ak+7][am] = a1.w;
    Bs[bk+0][bn] = b0.x; Bs[bk+1][bn] = b0.y; Bs[bk+2][bn] = b0.z; Bs[bk+3][bn] = b0.w;
    __syncthreads();
    #pragma unroll
    for (int k = 0; k < 16; k++) {
      float a[8], b[4];
      *(float4*)&a[0] = *(const float4*)&As[k][ty*8];
      *(float4*)&a[4] = *(const float4*)&As[k][ty*8+4];
      *(float4*)&b[0] = *(const float4*)&Bs[k][tx*4];
      #pragma unroll
      for (int i = 0; i < 8; i++)
        #pragma unroll
        for (int j = 0; j < 4; j++)
          acc[i][j] = fmaf(a[i], b[j], acc[i][j]);
    }
    __syncthreads();
  }

  float bv[4] = {0.f, 0.f, 0.f, 0.f};
  if (bias) {
    #pragma unroll
    for (int j = 0; j < 4; j++) bv[j] = bias[n0 + tx*4 + j];
  }
  #pragma unroll
  for (int i = 0; i < 8; i++) {
    float4 o;
    o.x = acc[i][0] + bv[0];
    o.y = acc[i][1] + bv[1];
    o.z = acc[i][2] + bv[2];
    o.w = acc[i][3] + bv[3];
    *(float4*)&C[(size_t)(m0 + ty*8 + i) * ldc + n0 + tx*4] = o;
  }
}

// ---------------------------------------------------------------------------
// GEMM (NT, fp32), BM=64, BN=64, BK=16, 256 threads, 4x4 outputs/thread.
// For the q projection: grid (16,32)=512 blocks -> 2 blocks/CU (the 128x64
// version gives only 256 blocks = 1 block/CU = 1 wave/SIMD, global-load
// latency fully exposed).
// ---------------------------------------------------------------------------
__global__ __launch_bounds__(256)
void gemm_nt_f32_64(const float* __restrict__ A, int lda,
                    const float* __restrict__ B, int ldb,
                    float* __restrict__ C, int ldc,
                    const float* __restrict__ bias, int K) {
  __shared__ float As[16][68];    // [k][m], pad 68 -> staging writes 2-way max
  __shared__ float Bs[16][68];    // [k][n]
  const int tid = threadIdx.x;
  const int tx = tid & 15;        // -> n (4 cols)
  const int ty = tid >> 4;        // -> m (4 rows)
  const int m0 = blockIdx.y * 64;
  const int n0 = blockIdx.x * 64;
  const int lm = tid >> 2;        // 0..63
  const int lk = (tid & 3) * 4;   // 0,4,8,12

  float acc[4][4];
  #pragma unroll
  for (int i = 0; i < 4; i++)
    #pragma unroll
    for (int j = 0; j < 4; j++) acc[i][j] = 0.f;

  const float* Arow = A + (size_t)(m0 + lm) * lda + lk;
  const float* Brow = B + (size_t)(n0 + lm) * ldb + lk;

  for (int kt = 0; kt < K; kt += 16) {
    float4 a0 = *(const float4*)(Arow + kt);
    float4 b0 = *(const float4*)(Brow + kt);
    As[lk+0][lm] = a0.x; As[lk+1][lm] = a0.y; As[lk+2][lm] = a0.z; As[lk+3][lm] = a0.w;
    Bs[lk+0][lm] = b0.x; Bs[lk+1][lm] = b0.y; Bs[lk+2][lm] = b0.z; Bs[lk+3][lm] = b0.w;
    __syncthreads();
    #pragma unroll
    for (int k = 0; k < 16; k++) {
      float a[4], b[4];
      *(float4*)&a[0] = *(const float4*)&As[k][ty*4];
      *(float4*)&b[0] = *(const float4*)&Bs[k][tx*4];
      #pragma unroll
      for (int i = 0; i < 4; i++)
        #pragma unroll
        for (int j = 0; j < 4; j++)
          acc[i][j] = fmaf(a[i], b[j], acc[i][j]);
    }
    __syncthreads();
  }

  float bv[4] = {0.f, 0.f, 0.f, 0.f};
  if (bias) {
    #pragma unroll
    for (int j = 0; j < 4; j++) bv[j] = bias[n0 + tx*4 + j];
  }
  #pragma unroll
  for (int i = 0; i < 4; i++) {
    float4 o;
    o.x = acc[i][0] + bv[0];
    o.y = acc[i][1] + bv[1];
    o.z = acc[i][2] + bv[2];
    o.w = acc[i][3] + bv[3];
    *(float4*)&C[(size_t)(m0 + ty*4 + i) * ldc + n0 + tx*4] = o;
  }
}

// ---------------------------------------------------------------------------
// Top-32 of 512 per row, one wave per row; 16384 rows of the fused score
// matrix s (row r = q-row r>>1, half r&1).  Output sorted DESCENDING, ties
// by ascending index (lax.top_k semantics; sortedness feeds combine's
// (i+1)(j+1)<=32 pruning).
//
// v2 algorithm: ballot-based bitwise binary search for the 32nd-largest
// ordered-uint (32 iters x 8 ballots, SGPR broadcast -> no shuffle
// reduce), ballot-prefix compaction of the 32 survivors to LDS, then a
// 15-step bitonic-32 sort.  Replaces 32 serial argmax rounds (~192
// dependent ds_swizzle) -> ~25x fewer DS ops, ~4x shorter dep chain.
// ---------------------------------------------------------------------------
__global__ __launch_bounds__(256)
void topk512(const float* __restrict__ s,
             float* __restrict__ v1, int* __restrict__ i1,
             float* __restrict__ v2, int* __restrict__ i2) {
  const int wid  = (int)((blockIdx.x * blockDim.x + threadIdx.x) >> 6);
  const int lane = threadIdx.x & 63;
  const int wv   = threadIdx.x >> 6;          // wave within block, 0..3
  const float* src = s + (size_t)wid * NKEYS;
  const int row = wid >> 1;
  float* dv = ((wid & 1) ? v2 : v1) + (size_t)row * KNN;
  int*   di = ((wid & 1) ? i2 : i1) + (size_t)row * KNN;

  // element index = k8*64 + lane (coalesced 256B loads)
  float v[8]; unsigned u[8];
  #pragma unroll
  for (int k8 = 0; k8 < 8; k8++) {
    float f = src[k8*64 + lane];
    v[k8] = f;
    unsigned b = __float_as_uint(f);
    u[k8] = (b & 0x80000000u) ? ~b : (b | 0x80000000u);  // order-preserving map
  }

  // T := largest t with count(u >= t) >= 32  == ordered-uint of the 32nd value
  unsigned T = 0u;
  for (int bit = 31; bit >= 0; bit--) {
    unsigned cand = T | (1u << bit);
    int cnt = 0;
    #pragma unroll
    for (int k8 = 0; k8 < 8; k8++)
      cnt += __popcll(__ballot(u[k8] >= cand));
    if (cnt >= KNN) T = cand;
  }

  // compact: all strict (u > T) first (count <= 31 by construction), then
  // equals in ascending element index until 32 filled.
  __shared__ float cval[4][KNN];
  __shared__ int   cidx[4][KNN];
  const unsigned long long lt = (1ull << lane) - 1ull;
  int base = 0;
  #pragma unroll
  for (int k8 = 0; k8 < 8; k8++) {
    unsigned long long m = __ballot(u[k8] > T);
    if (u[k8] > T) {
      int p = base + __popcll(m & lt);
      cval[wv][p] = v[k8];
      cidx[wv][p] = k8*64 + lane;
    }
    base += __popcll(m);
  }
  #pragma unroll
  for (int k8 = 0; k8 < 8; k8++) {
    unsigned long long m = __ballot(u[k8] == T);
    if (u[k8] == T) {
      int p = base + __popcll(m & lt);
      if (p < KNN) { cval[wv][p] = v[k8]; cidx[wv][p] = k8*64 + lane; }
    }
    base += __popcll(m);
  }
  __syncthreads();   // LDS RAW across lanes (per-wave buffers, block-uniform path)

  // bitonic sort of 32 (lanes 0..31 real, distances <=16 stay in-half);
  // descending by value, ties ascending by index (total order).
  float sv = (lane < KNN) ? cval[wv][lane] : -INFINITY;
  int   sx = (lane < KNN) ? cidx[wv][lane] : 0x7fffffff;
  #pragma unroll
  for (int k = 2; k <= KNN; k <<= 1) {
    #pragma unroll
    for (int j = k >> 1; j >= 1; j >>= 1) {
      float ov = __shfl_xor(sv, j, 64);
      int   ox = __shfl_xor(sx, j, 64);
      bool keepmax = (((lane & j) == 0) == ((lane & k) == 0));
      bool ogt = (ov > sv) || (ov == sv && ox < sx);
      if (keepmax ? ogt : !ogt) { sv = ov; sx = ox; }
    }
  }
  if (lane < KNN) { dv[lane] = sv; di[lane] = sx; }
}

// ---------------------------------------------------------------------------
// Combine: per q-row, top-32 of {a_i + b_j}. Since a,b sorted descending, a
// pair can only be top-32 if (i+1)*(j+1) <= 32 -> 119 candidates. One wave
// per row: 2 candidates/lane, bitonic sort of 128 (val,pairIdx) descending
// via shfl, take first 32, softmax, write weights + flat value indices.
// ---------------------------------------------------------------------------
__global__ __launch_bounds__(256)
void combine_topk(const float* __restrict__ v1, const int* __restrict__ i1,
                  const float* __restrict__ v2, const int* __restrict__ i2,
                  float* __restrict__ wout, int* __restrict__ idxout) {
  const int wid  = (int)((blockIdx.x * blockDim.x + threadIdx.x) >> 6);
  const int lane = threadIdx.x & 63;

  const float* a  = v1 + (size_t)wid * KNN;
  const int*   ai = i1 + (size_t)wid * KNN;
  const float* b  = v2 + (size_t)wid * KNN;
  const int*   bi = i2 + (size_t)wid * KNN;

  float cv[2]; int cidx[2];
  #pragma unroll
  for (int h = 0; h < 2; h++) {
    int t = lane + h*64;
    int i = 0, rem = t;
    while (i < 32 && rem >= 32/(i+1)) { rem -= 32/(i+1); i++; }
    if (i < 32) {               // valid candidate (t < 119)
      float av = a[i], bvv = b[rem];
      cv[h]   = av + bvv;
      cidx[h] = ai[i] * NKEYS + bi[rem];
    } else {
      cv[h] = -INFINITY; cidx[h] = 0;
    }
  }

  // bitonic sort of 128 elements (element e = 2*lane + h), descending
  #pragma unroll
  for (int k = 2; k <= 128; k <<= 1) {
    #pragma unroll
    for (int j = 64; j >= 1; j >>= 1) {
      if (j > (k >> 1)) continue;
      if (j >= 2) {
        int mdist = j >> 1;
        #pragma unroll
        for (int h = 0; h < 2; h++) {
          float ov = __shfl_xor(cv[h],   mdist, 64);
          int   oi = __shfl_xor(cidx[h], mdist, 64);
          int e = 2*lane + h;
          bool lower   = (lane & mdist) == 0;
          bool desc    = (e & k) == 0;
          bool keepmax = (lower == desc);
          bool take    = keepmax ? (ov > cv[h]) : (ov < cv[h]);
          if (take) { cv[h] = ov; cidx[h] = oi; }
        }
      } else {
        int e = 2*lane;
        bool desc = (e & k) == 0;
        bool sw = desc ? (cv[0] < cv[1]) : (cv[0] > cv[1]);
        if (sw) {
          float tv = cv[0]; cv[0] = cv[1]; cv[1] = tv;
          int  ti = cidx[0]; cidx[0] = cidx[1]; cidx[1] = ti;
        }
      }
    }
  }

  // elements 0..31 live in lanes 0..15 (both slots); element 0 is the max
  float mx = __shfl(cv[0], 0, 64);
  float e0 = (lane < 16) ? __expf(cv[0] - mx) : 0.f;
  float e1 = (lane < 16) ? __expf(cv[1] - mx) : 0.f;
  float ssum = e0 + e1;
  #pragma unroll
  for (int off = 32; off >= 1; off >>= 1) ssum += __shfl_xor(ssum, off, 64);

  if (lane < 16) {
    size_t base = (size_t)wid * KNN + 2*lane;
    wout[base]     = e0 / ssum;
    wout[base + 1] = e1 / ssum;
    idxout[base]     = cidx[0];
    idxout[base + 1] = cidx[1];
  }
}

// ---------------------------------------------------------------------------
// Gather: out[b,:] = sum_k w[b,k] * values[idx[b,k], :].  One block per b,
// 256 threads x float4 = 1024 cols. 1 GB of coalesced 4KB-row reads -> the
// HBM roofline of this problem.
// ---------------------------------------------------------------------------
__global__ __launch_bounds__(256)
void gather_wsum(const float* __restrict__ w, const int* __restrict__ idx,
                 const float* __restrict__ values, float* __restrict__ out) {
  const int b = blockIdx.x;
  const int t = threadIdx.x;
  __shared__ float sw[128];
  __shared__ int   si[128];
  if (t < 128) {
    sw[t] = w[(size_t)b*128 + t];
    si[t] = idx[(size_t)b*128 + t];
  }
  __syncthreads();
  const float4* V = (const float4*)values;   // row stride 256 float4
  float4 acc = make_float4(0.f, 0.f, 0.f, 0.f);
  #pragma unroll 8
  for (int k = 0; k < 128; k++) {
    float wk = sw[k];
    float4 v = V[(size_t)si[k] * 256 + t];
    acc.x = fmaf(wk, v.x, acc.x);
    acc.y = fmaf(wk, v.y, acc.y);
    acc.z = fmaf(wk, v.z, acc.z);
    acc.w = fmaf(wk, v.w, acc.w);
  }
  ((float4*)out)[(size_t)b*256 + t] = acc;
}

// ---------------------------------------------------------------------------
extern "C" void kernel_launch(void* const* d_in, const int* in_sizes, int n_in,
                              void* d_out, int out_size, void* d_ws, size_t ws_size,
                              hipStream_t stream) {
  const float* x      = (const float*)d_in[0];   // 2048 x 1024
  const float* Wq     = (const float*)d_in[1];   // 1024 x 1024
  const float* bq     = (const float*)d_in[2];   // 1024
  const float* keys   = (const float*)d_in[3];   // 512 x 128
  const float* values = (const float*)d_in[4];   // 262144 x 1024
  float* out = (float*)d_out;

  char* ws = (char*)d_ws;
  float* q   = (float*)(ws);                     // 8 MB   (8192 x 256 == 16384 x 128)
  float* s   = (float*)(ws + (8u  << 20));       // 32 MB  (16384 x 512)
  float* v1  = (float*)(ws + (40u << 20));       // 1 MB   (8192 x 32)
  int*   i1  = (int*)  (ws + (41u << 20));
  float* v2  = (float*)(ws + (42u << 20));
  int*   i2  = (int*)  (ws + (43u << 20));
  float* wsc = (float*)(ws + (44u << 20));       // softmax weights
  int*   fid = (int*)  (ws + (45u << 20));       // flat value indices

  // q = x @ Wq^T + bq   (2048x1024, K=1024) — 64x64 tiles: 512 blocks, 2/CU
  gemm_nt_f32_64<<<dim3(1024/64, 2048/64), 256, 0, stream>>>(x, 1024, Wq, 1024, q, 1024, bq, 1024);
  // fused scores: q viewed as 16384x128 (row 2r = q1 of row r, 2r+1 = q2);
  // both halves use the same keys -> one GEMM, 1024 blocks, 4/CU
  gemm_nt_f32<<<dim3(512/64, 16384/128), 256, 0, stream>>>(q, 128, keys, 128, s, 512, nullptr, 128);
  // per-row top-32 of 512 (both halves), sorted descending
  topk512<<<4096, 256, 0, stream>>>(s, v1, i1, v2, i2);
  // pairwise top-32 + softmax
  combine_topk<<<2048, 256, 0, stream>>>(v1, i1, v2, i2, wsc, fid);
  // weighted gather
  gather_wsum<<<2048, 256, 0, stream>>>(wsc, fid, values, out);
}